// Round 10
// baseline (39.618 us; speedup 1.0000x reference)
//
#include <hip/hip_runtime.h>
#include <stdint.h>

#define NA   3
#define KCH  8       // 5 + NUM_CLASSES
#define BLK  1024
#define NWV  (BLK / 64)
#define NB   2048    // histogram bins (stage1: key>>21; stage2: (key>>10)&2047)
#define QCAP 768

#define LOG2E 1.4426950408889634f
#define LN2   0.6931471805599453f

struct ScaleParams {
  const float*   pred;    // (B, 24, H, W)
  const float*   boxes;   // (B, N, 4)
  const int*     labels;  // (B, N)
  const uint8_t* pos;     // (B, N) bool
  const uint8_t* neg;     // (B, N) bool
  int HW;
};

__device__ __forceinline__ float fexp2(float x) { return __builtin_amdgcn_exp2f(x); }
__device__ __forceinline__ float flog2(float x) { return __builtin_amdgcn_logf(x); }

// logaddexp(0,x) = max(x,0) + log1p(exp(-|x|)); native exp2/log2, ~1e-6 rel
__device__ __forceinline__ float softplus_fast(float x) {
  const float t = fexp2(-fabsf(x) * LOG2E);
  return fmaxf(x, 0.f) + flog2(1.f + t) * LN2;
}

__device__ __forceinline__ float sl1f(float d) {
  float ad = fabsf(d);
  return (ad < 1.f) ? 0.5f * d * d : ad - 0.5f;
}

// order-preserving float->uint key (larger float => larger key)
__device__ __forceinline__ unsigned fkey(unsigned u) {
  return (u & 0x80000000u) ? ~u : (u | 0x80000000u);
}
__device__ __forceinline__ unsigned funkey(unsigned k) {
  return (k & 0x80000000u) ? (k & 0x7FFFFFFFu) : ~k;
}

__device__ __forceinline__ float blockSum(float v, float* scr) {
  #pragma unroll
  for (int off = 32; off > 0; off >>= 1) v += __shfl_down(v, off);
  const int lane = threadIdx.x & 63, w = threadIdx.x >> 6;
  __syncthreads();                       // protect scr reuse
  if (lane == 0) scr[w] = v;
  __syncthreads();
  float r = 0.f;
  #pragma unroll
  for (int i = 0; i < NWV; ++i) r += scr[i];   // same-address broadcast
  return r;
}

// Per-thread 2 consecutive bins (count, value-sum) of an ascending-key hist:
// find bin holding the krem-th LARGEST, remaining count inside it, and the
// value-sum of all strictly-higher bins (+ sa_in). Block-uniform; out in sh_*.
__device__ __forceinline__ void selectDigit2(const unsigned* cb, const float* sb,
    int krem_in, float sa_in, int* iwav, float* fwav,
    int* sh_dig, int* sh_krem, float* sh_sa) {
  const int t = threadIdx.x, lane = t & 63, w = t >> 6;
  int c_t = (int)cb[0] + (int)cb[1];
  float s_t = sb[0] + sb[1];
  int ci = c_t; float si = s_t;          // wave inclusive suffix scan
  #pragma unroll
  for (int off = 1; off < 64; off <<= 1) {
    const int   co = __shfl_down(ci, off);
    const float so = __shfl_down(si, off);
    if (lane + off < 64) { ci += co; si += so; }
  }
  __syncthreads();                       // protect iwav/fwav reuse
  if (lane == 0) { iwav[w] = ci; fwav[w] = si; }
  __syncthreads();
  int ac = 0; float as = 0.f;
  #pragma unroll
  for (int w2 = 0; w2 < NWV; ++w2)
    if (w2 > w) { ac += iwav[w2]; as += fwav[w2]; }
  int   cum_c = (ci - c_t) + ac;         // strictly above this thread's top bin
  float cum_s = (si - s_t) + as;
  #pragma unroll
  for (int q = 1; q >= 0; --q) {
    const int cq = (int)cb[q];
    if (cq > 0 && cum_c < krem_in && krem_in <= cum_c + cq) {  // unique
      *sh_dig  = t * 2 + q;
      *sh_krem = krem_in - cum_c;
      *sh_sa   = sa_in + cum_s;
    }
    cum_c += cq; cum_s += sb[q];
  }
  __syncthreads();
}

__global__ void k_zero(float* out, unsigned* done) {
  if (threadIdx.x < 4) out[threadIdx.x] = 0.f;
  if (threadIdx.x == 0) *done = 0u;
}

// One block per (scale, batch) row. 16 waves, ILP-2 sweeps, 2-stage select.
__global__ __launch_bounds__(BLK, 8) void k_row(
    ScaleParams p0, ScaleParams p1, ScaleParams p2,
    int B, int R, float invB, float* out, unsigned* done) {
  __shared__ unsigned hc[NB];
  __shared__ float    hs[NB];
  __shared__ int      queue[QCAP];
  __shared__ int      sh_qn;
  __shared__ int      iwav[NWV];
  __shared__ float    fwav[NWV], fscr[NWV];
  __shared__ int      sh_dig, sh_krem;
  __shared__ float    sh_sa;

  const int r = blockIdx.x;
  const int s = (r >= B) + (r >= 2 * B);   // heavy s0 rows dispatched first
  const int b = r - s * B;
  const ScaleParams P = (s == 0) ? p0 : (s == 1) ? p1 : p2;
  const int HW = P.HW, N = NA * HW;
  const int t = threadIdx.x;

  for (int i = t; i < NB; i += BLK) hc[i] = 0u;
  if (t == 0) sh_qn = 0;
  __syncthreads();

  const float* predb = P.pred + (size_t)b * (NA * KCH) * HW;
  const size_t row = (size_t)b * N;
  float nneg = 0.f;

  // ---- sweep 1: counts-only raw-key histogram + pos queue (ILP-2) ----
  for (int c8 = t * 8; c8 < N; c8 += BLK * 8) {
    const int a = (c8 >= HW) + (c8 >= 2 * HW);
    const int cell = c8 - a * HW;
    const float* po = predb + (size_t)a * KCH * HW + 4 * HW + cell;
    const float4 o0 = *(const float4*)po;          // independent loads:
    const float4 o1 = *(const float4*)(po + 4);    // 2x16B + 2x8B in flight
    const uint2 pmv = *(const uint2*)(P.pos + row + c8);
    const uint2 nmv = *(const uint2*)(P.neg + row + c8);
    #pragma unroll
    for (int q = 0; q < 4; ++q) {
      if ((nmv.x >> (8 * q)) & 0xFFu) {
        nneg += 1.f;
        atomicAdd(&hc[fkey(__float_as_uint((&o0.x)[q])) >> 21], 1u);
      }
      if ((pmv.x >> (8 * q)) & 0xFFu) {
        const int idx = atomicAdd(&sh_qn, 1);
        if (idx < QCAP) queue[idx] = c8 + q;
      }
    }
    #pragma unroll
    for (int q = 0; q < 4; ++q) {
      if ((nmv.y >> (8 * q)) & 0xFFu) {
        nneg += 1.f;
        atomicAdd(&hc[fkey(__float_as_uint((&o1.x)[q])) >> 21], 1u);
      }
      if ((pmv.y >> (8 * q)) & 0xFFu) {
        const int idx = atomicAdd(&sh_qn, 1);
        if (idx < QCAP) queue[idx] = c8 + 4 + q;
      }
    }
  }
  __syncthreads();
  const int npos = sh_qn;
  const int qn = min(npos, QCAP);

  // ---- dense pos-anchor work (~1%): softplus/CE/smooth-L1, L2-hot ----
  float posobj = 0.f, ce = 0.f, loc = 0.f;
  for (int i = t; i < qn; i += BLK) {
    const int j = queue[i];
    const int a = (j >= HW) + (j >= 2 * HW);
    const int cell = j - a * HW;
    const float* pa = predb + (size_t)a * KCH * HW;
    posobj += softplus_fast(-pa[4 * HW + cell]);     // sp(x)-x == sp(-x)
    const float c0f = pa[5 * HW + cell];
    const float c1f = pa[6 * HW + cell];
    const float c2f = pa[7 * HW + cell];
    const float m = fmaxf(fmaxf(c0f, c1f), c2f);
    const float e = fexp2((c0f - m) * LOG2E) + fexp2((c1f - m) * LOG2E)
                  + fexp2((c2f - m) * LOG2E);
    const float lse = m + flog2(e) * LN2;
    const int lab = P.labels[row + j];
    ce += lse - ((lab == 0) ? c0f : (lab == 1) ? c1f : c2f);
    const float4 bx = *(const float4*)(P.boxes + (size_t)(row + j) * 4);
    loc += sl1f(pa[0 * HW + cell] - bx.x) + sl1f(pa[1 * HW + cell] - bx.y)
         + sl1f(pa[2 * HW + cell] - bx.z) + sl1f(pa[3 * HW + cell] - bx.w);
  }

  const float t_nneg = blockSum(nneg, fscr);
  const float t_po   = blockSum(posobj, fscr);
  const float t_ce   = blockSum(ce, fscr);
  const float t_lc   = blockSum(loc, fscr);
  const int k = min(3 * npos, (int)t_nneg);

  float sel = 0.f;
  if (k > 0) {  // block-uniform
    // ---- stage 1: bits[31:21], counts only ----
    unsigned cb[2]; float sb[2];
    cb[0] = hc[2 * t]; cb[1] = hc[2 * t + 1]; sb[0] = 0.f; sb[1] = 0.f;
    selectDigit2(cb, sb, k, 0.f, iwav, fwav, &sh_dig, &sh_krem, &sh_sa);
    const int bin1 = sh_dig; const int krem1 = sh_krem;

    // ---- sweep 2 (L2-hot): sum above bin1; fine hist inside bin1 ----
    for (int i = t; i < NB; i += BLK) { hc[i] = 0u; hs[i] = 0.f; }
    __syncthreads();
    float sgt = 0.f;
    for (int c8 = t * 8; c8 < N; c8 += BLK * 8) {
      const int a = (c8 >= HW) + (c8 >= 2 * HW);
      const int cell = c8 - a * HW;
      const float* po = predb + (size_t)a * KCH * HW + 4 * HW + cell;
      const float4 o0 = *(const float4*)po;
      const float4 o1 = *(const float4*)(po + 4);
      const uint2 nmv = *(const uint2*)(P.neg + row + c8);
      #pragma unroll
      for (int q = 0; q < 4; ++q) {
        if ((nmv.x >> (8 * q)) & 0xFFu) {
          const float obj = (&o0.x)[q];
          const unsigned key = fkey(__float_as_uint(obj));
          const int kb = (int)(key >> 21);
          if (kb > bin1) sgt += softplus_fast(obj);        // ~3%
          else if (kb == bin1) {
            atomicAdd(&hc[(key >> 10) & (NB - 1)], 1u);
            atomicAdd(&hs[(key >> 10) & (NB - 1)], softplus_fast(obj));
          }
        }
      }
      #pragma unroll
      for (int q = 0; q < 4; ++q) {
        if ((nmv.y >> (8 * q)) & 0xFFu) {
          const float obj = (&o1.x)[q];
          const unsigned key = fkey(__float_as_uint(obj));
          const int kb = (int)(key >> 21);
          if (kb > bin1) sgt += softplus_fast(obj);
          else if (kb == bin1) {
            atomicAdd(&hc[(key >> 10) & (NB - 1)], 1u);
            atomicAdd(&hs[(key >> 10) & (NB - 1)], softplus_fast(obj));
          }
        }
      }
    }
    __syncthreads();
    const float t_sgt = blockSum(sgt, fscr);
    unsigned cb2[2]; float sb2[2];
    cb2[0] = hc[2 * t]; cb2[1] = hc[2 * t + 1];
    sb2[0] = hs[2 * t]; sb2[1] = hs[2 * t + 1];
    selectDigit2(cb2, sb2, krem1, t_sgt, iwav, fwav, &sh_dig, &sh_krem, &sh_sa);

    // 13 mantissa bits kept; tie-edge error <= krem2 * width ~ 1e-3, negligible
    const unsigned Tkey = ((unsigned)bin1 << 21) | ((unsigned)sh_dig << 10);
    sel = sh_sa + (float)sh_krem * softplus_fast(__uint_as_float(funkey(Tkey)));
  }

  if (t == 0) {
    const float denom = (float)max(npos, 1);
    atomicAdd(&out[1], (t_po + sel) / denom);
    if (npos > 0) {
      atomicAdd(&out[2], t_ce / denom);
      atomicAdd(&out[3], t_lc / (denom * 4.f));
    }
    __threadfence();
    const unsigned old = atomicAdd(done, 1u);
    if (old == (unsigned)(R - 1)) {          // last row finalizes in place
      const float o = atomicAdd(&out[1], 0.f) * invB;
      const float c = atomicAdd(&out[2], 0.f) * invB;
      const float l = atomicAdd(&out[3], 0.f) * invB;
      out[0] = o + c + l;
      out[1] = o;
      out[2] = c;
      out[3] = l;
    }
  }
}

extern "C" void kernel_launch(void* const* d_in, const int* in_sizes, int n_in,
                              void* d_out, int out_size, void* d_ws, size_t ws_size,
                              hipStream_t stream) {
  (void)n_in; (void)out_size; (void)ws_size;

  const int HW0 = 80 * 80, HW1 = 40 * 40, HW2 = 20 * 20;
  const int B = in_sizes[0] / (NA * KCH * HW0);
  const int R = 3 * B;
  const float invB = 1.f / (float)B;

  ScaleParams p0{(const float*)d_in[0],  (const float*)d_in[1],
                 (const int*)d_in[2],    (const uint8_t*)d_in[3],
                 (const uint8_t*)d_in[4], HW0};
  ScaleParams p1{(const float*)d_in[5],  (const float*)d_in[6],
                 (const int*)d_in[7],    (const uint8_t*)d_in[8],
                 (const uint8_t*)d_in[9], HW1};
  ScaleParams p2{(const float*)d_in[10], (const float*)d_in[11],
                 (const int*)d_in[12],   (const uint8_t*)d_in[13],
                 (const uint8_t*)d_in[14], HW2};

  float* out = (float*)d_out;
  unsigned* done = (unsigned*)d_ws;

  k_zero<<<1, 64, 0, stream>>>(out, done);
  k_row<<<R, BLK, 0, stream>>>(p0, p1, p2, B, R, invB, out, done);
}

// Round 11
// 35.016 us; speedup vs baseline: 1.1314x; 1.1314x over previous
//
#include <hip/hip_runtime.h>
#include <stdint.h>

#define NA   3
#define KCH  8       // 5 + NUM_CLASSES
#define BLK  512
#define NWV  (BLK / 64)
#define NB   2048    // stage-1 bins: key16 >> 5 (sign+8exp+2mant)
#define MAXN 19200   // 3 * 80 * 80
#define QCAP 512

#define LOG2E 1.4426950408889634f
#define LN2   0.6931471805599453f

struct ScaleParams {
  const float*   pred;    // (B, 24, H, W)
  const float*   boxes;   // (B, N, 4)
  const int*     labels;  // (B, N)
  const uint8_t* pos;     // (B, N) bool
  const uint8_t* neg;     // (B, N) bool
  int HW;
};

__device__ __forceinline__ float fexp2(float x) { return __builtin_amdgcn_exp2f(x); }
__device__ __forceinline__ float flog2(float x) { return __builtin_amdgcn_logf(x); }

// logaddexp(0,x) = max(x,0) + log1p(exp(-|x|)); native exp2/log2, ~1e-6 rel
__device__ __forceinline__ float softplus_fast(float x) {
  const float t = fexp2(-fabsf(x) * LOG2E);
  return fmaxf(x, 0.f) + flog2(1.f + t) * LN2;
}

__device__ __forceinline__ float sl1f(float d) {
  float ad = fabsf(d);
  return (ad < 1.f) ? 0.5f * d * d : ad - 0.5f;
}

// order-preserving float->uint key (larger float => larger key)
__device__ __forceinline__ unsigned fkey(unsigned u) {
  return (u & 0x80000000u) ? ~u : (u | 0x80000000u);
}
__device__ __forceinline__ unsigned funkey(unsigned k) {
  return (k & 0x80000000u) ? (k & 0x7FFFFFFFu) : ~k;
}

// reconstruct approx value from 16-bit key (midpoint of the key interval)
__device__ __forceinline__ float recon16(unsigned k16) {
  return __uint_as_float(funkey((k16 << 16) | 0x8000u));
}

__device__ __forceinline__ float blockSum(float v, float* scr) {
  #pragma unroll
  for (int off = 32; off > 0; off >>= 1) v += __shfl_down(v, off);
  const int lane = threadIdx.x & 63, w = threadIdx.x >> 6;
  __syncthreads();                       // protect scr reuse
  if (lane == 0) scr[w] = v;
  __syncthreads();
  float r = 0.f;
  #pragma unroll
  for (int i = 0; i < NWV; ++i) r += scr[i];   // same-address broadcast
  return r;
}

// Stage-1 select: per-thread 4 consecutive bins (counts only) of ascending-key
// hist; find bin holding the krem-th LARGEST and remaining count inside it.
__device__ __forceinline__ void selectBin1(const unsigned* cb, int krem_in,
    int* iwav, int* sh_dig, int* sh_krem) {
  const int t = threadIdx.x, lane = t & 63, w = t >> 6;
  const int c_t = (int)(cb[0] + cb[1] + cb[2] + cb[3]);
  int ci = c_t;                          // wave inclusive suffix scan
  #pragma unroll
  for (int off = 1; off < 64; off <<= 1) {
    const int co = __shfl_down(ci, off);
    if (lane + off < 64) ci += co;
  }
  __syncthreads();                       // protect iwav reuse
  if (lane == 0) iwav[w] = ci;
  __syncthreads();
  int ac = 0;
  #pragma unroll
  for (int w2 = 0; w2 < NWV; ++w2) if (w2 > w) ac += iwav[w2];
  int cum_c = (ci - c_t) + ac;           // count strictly above thread's top bin
  #pragma unroll
  for (int q = 3; q >= 0; --q) {
    const int cq = (int)cb[q];
    if (cq > 0 && cum_c < krem_in && krem_in <= cum_c + cq) {  // unique bracket
      *sh_dig  = t * 4 + q;
      *sh_krem = krem_in - cum_c;
    }
    cum_c += cq;
  }
  __syncthreads();
}

__global__ void k_zero(float* out, unsigned* done) {
  if (threadIdx.x < 4) out[threadIdx.x] = 0.f;
  if (threadIdx.x == 0) *done = 0u;
}

// One block per (scale, batch) row. Sweep1 (global) caches 16-bit keys in LDS;
// sweep2 + both select stages run entirely from LDS.
__global__ __launch_bounds__(BLK) void k_row(
    ScaleParams p0, ScaleParams p1, ScaleParams p2,
    int B, int R, float invB, float* out, unsigned* done) {
  __shared__ unsigned short keys[MAXN];   // 38.4 KB: key16 (0 = not-neg)
  __shared__ unsigned hc[NB];             // 8 KB
  __shared__ int      queue[QCAP];
  __shared__ int      sh_qn;
  __shared__ int      iwav[NWV];
  __shared__ float    fscr[NWV];
  __shared__ int      sh_dig, sh_krem;
  __shared__ float    sh_sa, sh_avg;
  __shared__ unsigned c32[32];
  __shared__ float    s32[32];

  const int r = blockIdx.x;
  const int s = (r >= B) + (r >= 2 * B);  // heavy s0 rows dispatched first
  const int b = r - s * B;
  const ScaleParams P = (s == 0) ? p0 : (s == 1) ? p1 : p2;
  const int HW = P.HW, N = NA * HW;
  const int t = threadIdx.x;

  for (int i = t; i < NB; i += BLK) hc[i] = 0u;
  if (t == 0) sh_qn = 0;
  __syncthreads();

  const float* predb = P.pred + (size_t)b * (NA * KCH) * HW;
  const size_t row = (size_t)b * N;
  float nneg = 0.f;

  // ---- sweep 1 (global): keys -> LDS, 2048-bin count hist, pos queue ----
  for (int c8 = t * 8; c8 < N; c8 += BLK * 8) {
    const int a = (c8 >= HW) + (c8 >= 2 * HW);
    const int cell = c8 - a * HW;
    const float* po = predb + (size_t)a * KCH * HW + 4 * HW + cell;
    const float4 o0 = *(const float4*)po;        // independent loads in flight
    const float4 o1 = *(const float4*)(po + 4);
    const uint2 pmv = *(const uint2*)(P.pos + row + c8);
    const uint2 nmv = *(const uint2*)(P.neg + row + c8);
    unsigned kk[8];
    #pragma unroll
    for (int q = 0; q < 8; ++q) {
      const float obj = (q < 4) ? (&o0.x)[q] : (&o1.x)[q - 4];
      const unsigned nm = (q < 4) ? (nmv.x >> (8 * q)) : (nmv.y >> (8 * (q - 4)));
      const unsigned pm = (q < 4) ? (pmv.x >> (8 * q)) : (pmv.y >> (8 * (q - 4)));
      unsigned k16 = 0u;
      if (nm & 0xFFu) {
        nneg += 1.f;
        k16 = fkey(__float_as_uint(obj)) >> 16;
        k16 = max(k16, 1u);                      // 0 reserved for "not neg"
        atomicAdd(&hc[k16 >> 5], 1u);
      }
      kk[q] = k16;
      if (pm & 0xFFu) {
        const int idx = atomicAdd(&sh_qn, 1);
        if (idx < QCAP) queue[idx] = c8 + q;
      }
    }
    uint4 kv;
    kv.x = kk[0] | (kk[1] << 16); kv.y = kk[2] | (kk[3] << 16);
    kv.z = kk[4] | (kk[5] << 16); kv.w = kk[6] | (kk[7] << 16);
    *reinterpret_cast<uint4*>(&keys[c8]) = kv;
  }
  __syncthreads();
  const int npos = sh_qn;
  const int qn = min(npos, QCAP);

  // ---- dense pos-anchor work (~1%): softplus/CE/smooth-L1, L2-hot ----
  float posobj = 0.f, ce = 0.f, loc = 0.f;
  for (int i = t; i < qn; i += BLK) {
    const int j = queue[i];
    const int a = (j >= HW) + (j >= 2 * HW);
    const int cell = j - a * HW;
    const float* pa = predb + (size_t)a * KCH * HW;
    posobj += softplus_fast(-pa[4 * HW + cell]);     // sp(x)-x == sp(-x)
    const float c0f = pa[5 * HW + cell];
    const float c1f = pa[6 * HW + cell];
    const float c2f = pa[7 * HW + cell];
    const float m = fmaxf(fmaxf(c0f, c1f), c2f);
    const float e = fexp2((c0f - m) * LOG2E) + fexp2((c1f - m) * LOG2E)
                  + fexp2((c2f - m) * LOG2E);
    const float lse = m + flog2(e) * LN2;
    const int lab = P.labels[row + j];
    ce += lse - ((lab == 0) ? c0f : (lab == 1) ? c1f : c2f);
    const float4 bx = *(const float4*)(P.boxes + (size_t)(row + j) * 4);
    loc += sl1f(pa[0 * HW + cell] - bx.x) + sl1f(pa[1 * HW + cell] - bx.y)
         + sl1f(pa[2 * HW + cell] - bx.z) + sl1f(pa[3 * HW + cell] - bx.w);
  }

  const float t_nneg = blockSum(nneg, fscr);
  const float t_po   = blockSum(posobj, fscr);
  const float t_ce   = blockSum(ce, fscr);
  const float t_lc   = blockSum(loc, fscr);
  const int k = min(3 * npos, (int)t_nneg);

  float sel = 0.f;
  if (k > 0) {  // block-uniform
    // ---- stage 1: 11-bit bins, counts only (hist built in sweep 1) ----
    unsigned cb[4];
    #pragma unroll
    for (int q = 0; q < 4; ++q) cb[q] = hc[4 * t + q];
    selectBin1(cb, k, iwav, &sh_dig, &sh_krem);
    const int bin1 = sh_dig; const int krem1 = sh_krem;

    if (t < 32) { c32[t] = 0u; s32[t] = 0.f; }
    __syncthreads();

    // ---- sweep 2 (LDS only): sum above bin1; 32-bin refine inside bin1 ----
    float sgt = 0.f;
    for (int c8 = t * 8; c8 < N; c8 += BLK * 8) {
      const uint4 kv = *reinterpret_cast<const uint4*>(&keys[c8]);
      const unsigned ks[8] = {kv.x & 0xFFFFu, kv.x >> 16, kv.y & 0xFFFFu,
                              kv.y >> 16,     kv.z & 0xFFFFu, kv.z >> 16,
                              kv.w & 0xFFFFu, kv.w >> 16};
      #pragma unroll
      for (int q = 0; q < 8; ++q) {
        const unsigned k16 = ks[q];
        if (!k16) continue;
        const int kb = (int)(k16 >> 5);
        if (kb > bin1) sgt += softplus_fast(recon16(k16));       // ~3%
        else if (kb == bin1) {
          atomicAdd(&c32[k16 & 31u], 1u);
          atomicAdd(&s32[k16 & 31u], softplus_fast(recon16(k16)));
        }
      }
    }
    __syncthreads();
    const float t_sgt = blockSum(sgt, fscr);

    // ---- stage 2: 32 bins, one wave (lanes >=32 carry zeros) ----
    if (t < 64) {
      const int cc = (t < 32) ? (int)c32[t] : 0;
      const float ss = (t < 32) ? s32[t] : 0.f;
      int ci = cc; float si = ss;
      #pragma unroll
      for (int off = 1; off < 64; off <<= 1) {
        const int   co = __shfl_down(ci, off);
        const float so = __shfl_down(si, off);
        if ((t & 63) + off < 64) { ci += co; si += so; }
      }
      const int   above_c = ci - cc;     // count in bins strictly above t
      const float above_s = si - ss;
      if (t < 32 && cc > 0 && above_c < krem1 && krem1 <= above_c + cc) {
        sh_krem = krem1 - above_c;
        sh_sa   = t_sgt + above_s;
        sh_avg  = ss / (float)cc;        // tie-bin average (exact at key level)
      }
    }
    __syncthreads();
    sel = sh_sa + (float)sh_krem * sh_avg;
  }

  if (t == 0) {
    const float denom = (float)max(npos, 1);
    atomicAdd(&out[1], (t_po + sel) / denom);
    if (npos > 0) {
      atomicAdd(&out[2], t_ce / denom);
      atomicAdd(&out[3], t_lc / (denom * 4.f));
    }
    __threadfence();
    const unsigned old = atomicAdd(done, 1u);
    if (old == (unsigned)(R - 1)) {          // last row finalizes in place
      const float o = atomicAdd(&out[1], 0.f) * invB;
      const float c = atomicAdd(&out[2], 0.f) * invB;
      const float l = atomicAdd(&out[3], 0.f) * invB;
      out[0] = o + c + l;
      out[1] = o;
      out[2] = c;
      out[3] = l;
    }
  }
}

extern "C" void kernel_launch(void* const* d_in, const int* in_sizes, int n_in,
                              void* d_out, int out_size, void* d_ws, size_t ws_size,
                              hipStream_t stream) {
  (void)n_in; (void)out_size; (void)ws_size;

  const int HW0 = 80 * 80, HW1 = 40 * 40, HW2 = 20 * 20;
  const int B = in_sizes[0] / (NA * KCH * HW0);
  const int R = 3 * B;
  const float invB = 1.f / (float)B;

  ScaleParams p0{(const float*)d_in[0],  (const float*)d_in[1],
                 (const int*)d_in[2],    (const uint8_t*)d_in[3],
                 (const uint8_t*)d_in[4], HW0};
  ScaleParams p1{(const float*)d_in[5],  (const float*)d_in[6],
                 (const int*)d_in[7],    (const uint8_t*)d_in[8],
                 (const uint8_t*)d_in[9], HW1};
  ScaleParams p2{(const float*)d_in[10], (const float*)d_in[11],
                 (const int*)d_in[12],   (const uint8_t*)d_in[13],
                 (const uint8_t*)d_in[14], HW2};

  float* out = (float*)d_out;
  unsigned* done = (unsigned*)d_ws;

  k_zero<<<1, 64, 0, stream>>>(out, done);
  k_row<<<R, BLK, 0, stream>>>(p0, p1, p2, B, R, invB, out, done);
}

// Round 12
// 33.500 us; speedup vs baseline: 1.1826x; 1.0452x over previous
//
#include <hip/hip_runtime.h>
#include <stdint.h>

#define NA   3
#define KCH  8       // 5 + NUM_CLASSES
#define BLK  512
#define NWV  (BLK / 64)
#define NB   2048    // stage-1 bins: key16 >> 5 (sign+8exp+2mant)
#define MAXN 19200   // 3 * 80 * 80
#define QCAP 512

#define LOG2E 1.4426950408889634f
#define LN2   0.6931471805599453f

struct ScaleParams {
  const float*   pred;    // (B, 24, H, W)
  const float*   boxes;   // (B, N, 4)
  const int*     labels;  // (B, N)
  const uint8_t* pos;     // (B, N) bool
  const uint8_t* neg;     // (B, N) bool
  int HW;
};

__device__ __forceinline__ float fexp2(float x) { return __builtin_amdgcn_exp2f(x); }
__device__ __forceinline__ float flog2(float x) { return __builtin_amdgcn_logf(x); }

// logaddexp(0,x) = max(x,0) + log1p(exp(-|x|)); native exp2/log2, ~1e-6 rel
__device__ __forceinline__ float softplus_fast(float x) {
  const float t = fexp2(-fabsf(x) * LOG2E);
  return fmaxf(x, 0.f) + flog2(1.f + t) * LN2;
}

__device__ __forceinline__ float sl1f(float d) {
  float ad = fabsf(d);
  return (ad < 1.f) ? 0.5f * d * d : ad - 0.5f;
}

// order-preserving float->uint key (larger float => larger key)
__device__ __forceinline__ unsigned fkey(unsigned u) {
  return (u & 0x80000000u) ? ~u : (u | 0x80000000u);
}
__device__ __forceinline__ unsigned funkey(unsigned k) {
  return (k & 0x80000000u) ? (k & 0x7FFFFFFFu) : ~k;
}

// reconstruct approx value from 16-bit key (midpoint of the key interval)
__device__ __forceinline__ float recon16(unsigned k16) {
  return __uint_as_float(funkey((k16 << 16) | 0x8000u));
}

__device__ __forceinline__ float blockSum(float v, float* scr) {
  #pragma unroll
  for (int off = 32; off > 0; off >>= 1) v += __shfl_down(v, off);
  const int lane = threadIdx.x & 63, w = threadIdx.x >> 6;
  __syncthreads();                       // protect scr reuse
  if (lane == 0) scr[w] = v;
  __syncthreads();
  float r = 0.f;
  #pragma unroll
  for (int i = 0; i < NWV; ++i) r += scr[i];   // same-address broadcast
  return r;
}

// Stage-1 select: per-thread 4 consecutive bins (counts only) of ascending-key
// hist; find bin holding the krem-th LARGEST and remaining count inside it.
__device__ __forceinline__ void selectBin1(const unsigned* cb, int krem_in,
    int* iwav, int* sh_dig, int* sh_krem) {
  const int t = threadIdx.x, lane = t & 63, w = t >> 6;
  const int c_t = (int)(cb[0] + cb[1] + cb[2] + cb[3]);
  int ci = c_t;                          // wave inclusive suffix scan
  #pragma unroll
  for (int off = 1; off < 64; off <<= 1) {
    const int co = __shfl_down(ci, off);
    if (lane + off < 64) ci += co;
  }
  __syncthreads();                       // protect iwav reuse
  if (lane == 0) iwav[w] = ci;
  __syncthreads();
  int ac = 0;
  #pragma unroll
  for (int w2 = 0; w2 < NWV; ++w2) if (w2 > w) ac += iwav[w2];
  int cum_c = (ci - c_t) + ac;           // count strictly above thread's top bin
  #pragma unroll
  for (int q = 3; q >= 0; --q) {
    const int cq = (int)cb[q];
    if (cq > 0 && cum_c < krem_in && krem_in <= cum_c + cq) {  // unique bracket
      *sh_dig  = t * 4 + q;
      *sh_krem = krem_in - cum_c;
    }
    cum_c += cq;
  }
  __syncthreads();
}

__global__ void k_zero(float* out, unsigned* done) {
  if (threadIdx.x < 4) out[threadIdx.x] = 0.f;
  if (threadIdx.x == 0) *done = 0u;
}

struct RowShared {
  unsigned short keys[MAXN];   // 38.4 KB (0 = not-neg)
  unsigned hc[NB];             // 8 KB
  int      queue[QCAP];
  int      sh_qn;
  int      iwav[NWV];
  float    fscr[NWV];
  int      sh_dig, sh_krem;
  float    sh_sa, sh_avg;
  unsigned c32[32];
  float    s32[32];
};

// Whole-row processing with compile-time N: phase-A prefetch (all loads in
// flight) then phase-B process; LDS-only sweep 2; 2-stage select.
template<int N>
__device__ __forceinline__ void row_impl(
    const ScaleParams P, int b, int npos_unused, int R, float invB,
    float* out, unsigned* done, RowShared& S) {
  constexpr int HW = N / 3;
  constexpr int ITER = (N + BLK * 8 - 1) / (BLK * 8);
  const int t = threadIdx.x;

  for (int i = t; i < NB; i += BLK) S.hc[i] = 0u;
  if (t == 0) S.sh_qn = 0;
  __syncthreads();

  const float* predb = P.pred + (size_t)b * (NA * KCH) * HW;
  const size_t row = (size_t)b * N;
  float nneg = 0.f;

  // ---- sweep 1, phase A: issue ALL global loads (compile-time unroll) ----
  float4 o0[ITER], o1[ITER];
  uint2  pmv[ITER], nmv[ITER];
  #pragma unroll
  for (int it = 0; it < ITER; ++it) {
    const int c8 = it * (BLK * 8) + t * 8;
    if (c8 < N) {
      const int a = (c8 >= HW) + (c8 >= 2 * HW);
      const int cell = c8 - a * HW;
      const float* po = predb + (size_t)a * KCH * HW + 4 * HW + cell;
      o0[it]  = *(const float4*)po;
      o1[it]  = *(const float4*)(po + 4);
      pmv[it] = *(const uint2*)(P.pos + row + c8);
      nmv[it] = *(const uint2*)(P.neg + row + c8);
    }
  }

  // ---- sweep 1, phase B: keys -> LDS, 2048-bin count hist, pos queue ----
  #pragma unroll
  for (int it = 0; it < ITER; ++it) {
    const int c8 = it * (BLK * 8) + t * 8;
    if (c8 < N) {
      unsigned kk[8];
      #pragma unroll
      for (int q = 0; q < 8; ++q) {
        const float obj = (q < 4) ? (&o0[it].x)[q] : (&o1[it].x)[q - 4];
        const unsigned nm = (q < 4) ? (nmv[it].x >> (8 * q))
                                    : (nmv[it].y >> (8 * (q - 4)));
        const unsigned pm = (q < 4) ? (pmv[it].x >> (8 * q))
                                    : (pmv[it].y >> (8 * (q - 4)));
        unsigned k16 = 0u;
        if (nm & 0xFFu) {
          nneg += 1.f;
          k16 = fkey(__float_as_uint(obj)) >> 16;
          k16 = max(k16, 1u);                    // 0 reserved for "not neg"
          atomicAdd(&S.hc[k16 >> 5], 1u);
        }
        kk[q] = k16;
        if (pm & 0xFFu) {
          const int idx = atomicAdd(&S.sh_qn, 1);
          if (idx < QCAP) S.queue[idx] = c8 + q;
        }
      }
      uint4 kv;
      kv.x = kk[0] | (kk[1] << 16); kv.y = kk[2] | (kk[3] << 16);
      kv.z = kk[4] | (kk[5] << 16); kv.w = kk[6] | (kk[7] << 16);
      *reinterpret_cast<uint4*>(&S.keys[c8]) = kv;
    }
  }
  __syncthreads();
  const int npos = S.sh_qn;
  const int qn = min(npos, QCAP);

  // ---- dense pos-anchor work (~1%): softplus/CE/smooth-L1, L2-hot ----
  float posobj = 0.f, ce = 0.f, loc = 0.f;
  for (int i = t; i < qn; i += BLK) {
    const int j = S.queue[i];
    const int a = (j >= HW) + (j >= 2 * HW);
    const int cell = j - a * HW;
    const float* pa = predb + (size_t)a * KCH * HW;
    posobj += softplus_fast(-pa[4 * HW + cell]);     // sp(x)-x == sp(-x)
    const float c0f = pa[5 * HW + cell];
    const float c1f = pa[6 * HW + cell];
    const float c2f = pa[7 * HW + cell];
    const float m = fmaxf(fmaxf(c0f, c1f), c2f);
    const float e = fexp2((c0f - m) * LOG2E) + fexp2((c1f - m) * LOG2E)
                  + fexp2((c2f - m) * LOG2E);
    const float lse = m + flog2(e) * LN2;
    const int lab = P.labels[row + j];
    ce += lse - ((lab == 0) ? c0f : (lab == 1) ? c1f : c2f);
    const float4 bx = *(const float4*)(P.boxes + (size_t)(row + j) * 4);
    loc += sl1f(pa[0 * HW + cell] - bx.x) + sl1f(pa[1 * HW + cell] - bx.y)
         + sl1f(pa[2 * HW + cell] - bx.z) + sl1f(pa[3 * HW + cell] - bx.w);
  }

  const float t_nneg = blockSum(nneg, S.fscr);
  const float t_po   = blockSum(posobj, S.fscr);
  const float t_ce   = blockSum(ce, S.fscr);
  const float t_lc   = blockSum(loc, S.fscr);
  const int k = min(3 * npos, (int)t_nneg);

  float sel = 0.f;
  if (k > 0) {  // block-uniform
    // ---- stage 1: 11-bit bins, counts only ----
    unsigned cb[4];
    #pragma unroll
    for (int q = 0; q < 4; ++q) cb[q] = S.hc[4 * t + q];
    selectBin1(cb, k, S.iwav, &S.sh_dig, &S.sh_krem);
    const int bin1 = S.sh_dig; const int krem1 = S.sh_krem;

    if (t < 32) { S.c32[t] = 0u; S.s32[t] = 0.f; }
    __syncthreads();

    // ---- sweep 2 (LDS only): sum above bin1; 32-bin refine inside bin1 ----
    float sgt = 0.f;
    #pragma unroll
    for (int it = 0; it < ITER; ++it) {
      const int c8 = it * (BLK * 8) + t * 8;
      if (c8 < N) {
        const uint4 kv = *reinterpret_cast<const uint4*>(&S.keys[c8]);
        const unsigned ks[8] = {kv.x & 0xFFFFu, kv.x >> 16, kv.y & 0xFFFFu,
                                kv.y >> 16,     kv.z & 0xFFFFu, kv.z >> 16,
                                kv.w & 0xFFFFu, kv.w >> 16};
        #pragma unroll
        for (int q = 0; q < 8; ++q) {
          const unsigned k16 = ks[q];
          if (!k16) continue;
          const int kb = (int)(k16 >> 5);
          if (kb > bin1) sgt += softplus_fast(recon16(k16));     // ~3%
          else if (kb == bin1) {
            atomicAdd(&S.c32[k16 & 31u], 1u);
            atomicAdd(&S.s32[k16 & 31u], softplus_fast(recon16(k16)));
          }
        }
      }
    }
    __syncthreads();
    const float t_sgt = blockSum(sgt, S.fscr);

    // ---- stage 2: 32 bins, one wave (lanes >=32 carry zeros) ----
    if (t < 64) {
      const int cc = (t < 32) ? (int)S.c32[t] : 0;
      const float ss = (t < 32) ? S.s32[t] : 0.f;
      int ci = cc; float si = ss;
      #pragma unroll
      for (int off = 1; off < 64; off <<= 1) {
        const int   co = __shfl_down(ci, off);
        const float so = __shfl_down(si, off);
        if ((t & 63) + off < 64) { ci += co; si += so; }
      }
      const int   above_c = ci - cc;     // count in bins strictly above t
      const float above_s = si - ss;
      if (t < 32 && cc > 0 && above_c < krem1 && krem1 <= above_c + cc) {
        S.sh_krem = krem1 - above_c;
        S.sh_sa   = t_sgt + above_s;
        S.sh_avg  = ss / (float)cc;      // tie-bin average (exact at key level)
      }
    }
    __syncthreads();
    sel = S.sh_sa + (float)S.sh_krem * S.sh_avg;
  }

  if (t == 0) {
    const float denom = (float)max(npos, 1);
    atomicAdd(&out[1], (t_po + sel) / denom);
    if (npos > 0) {
      atomicAdd(&out[2], t_ce / denom);
      atomicAdd(&out[3], t_lc / (denom * 4.f));
    }
    __threadfence();
    const unsigned old = atomicAdd(done, 1u);
    if (old == (unsigned)(R - 1)) {          // last row finalizes in place
      const float o = atomicAdd(&out[1], 0.f) * invB;
      const float c = atomicAdd(&out[2], 0.f) * invB;
      const float l = atomicAdd(&out[3], 0.f) * invB;
      out[0] = o + c + l;
      out[1] = o;
      out[2] = c;
      out[3] = l;
    }
  }
}

__global__ __launch_bounds__(BLK) void k_row(
    ScaleParams p0, ScaleParams p1, ScaleParams p2,
    int B, int R, float invB, float* out, unsigned* done) {
  __shared__ RowShared S;
  const int r = blockIdx.x;
  const int s = (r >= B) + (r >= 2 * B);   // heavy s0 rows dispatched first
  const int b = r - s * B;
  if (s == 0)      row_impl<19200>(p0, b, 0, R, invB, out, done, S);
  else if (s == 1) row_impl<4800>(p1, b, 0, R, invB, out, done, S);
  else             row_impl<1200>(p2, b, 0, R, invB, out, done, S);
}

extern "C" void kernel_launch(void* const* d_in, const int* in_sizes, int n_in,
                              void* d_out, int out_size, void* d_ws, size_t ws_size,
                              hipStream_t stream) {
  (void)n_in; (void)out_size; (void)ws_size;

  const int HW0 = 80 * 80, HW1 = 40 * 40, HW2 = 20 * 20;
  const int B = in_sizes[0] / (NA * KCH * HW0);
  const int R = 3 * B;
  const float invB = 1.f / (float)B;

  ScaleParams p0{(const float*)d_in[0],  (const float*)d_in[1],
                 (const int*)d_in[2],    (const uint8_t*)d_in[3],
                 (const uint8_t*)d_in[4], HW0};
  ScaleParams p1{(const float*)d_in[5],  (const float*)d_in[6],
                 (const int*)d_in[7],    (const uint8_t*)d_in[8],
                 (const uint8_t*)d_in[9], HW1};
  ScaleParams p2{(const float*)d_in[10], (const float*)d_in[11],
                 (const int*)d_in[12],   (const uint8_t*)d_in[13],
                 (const uint8_t*)d_in[14], HW2};

  float* out = (float*)d_out;
  unsigned* done = (unsigned*)d_ws;

  k_zero<<<1, 64, 0, stream>>>(out, done);
  k_row<<<R, BLK, 0, stream>>>(p0, p1, p2, B, R, invB, out, done);
}